// Round 6
// baseline (303.428 us; speedup 1.0000x reference)
//
#include <hip/hip_runtime.h>

#define B_ 8
#define L_ 2048
#define E_ 256
#define H_ 4
#define D_ 64

typedef __bf16 bf16;
typedef __bf16 bf16x8 __attribute__((ext_vector_type(8)));
typedef __bf16 bf16x4 __attribute__((ext_vector_type(4)));
typedef float  f32x4  __attribute__((ext_vector_type(4)));
typedef float  f32x8  __attribute__((ext_vector_type(8)));
typedef float  f32x16 __attribute__((ext_vector_type(16)));

// Shat = (q.k)/8 * log2(e); softmax entirely in exp2 domain.
#define QSCALE 0.1803368801111244f

__device__ __forceinline__ float fexp2(float x) { return __builtin_amdgcn_exp2f(x); }
__device__ __forceinline__ float flog2(float x) { return __builtin_amdgcn_logf(x); }

// ---------------------------------------------------------------------------
// Kernel 1: repack weights to bf16.
// Wcat[768][256]: rows 0..511 = in_proj_w rows (q,k); rows 512..767 = W_gnn^T
// ---------------------------------------------------------------------------
__global__ void prep_weights(const float* __restrict__ in_proj_w,
                             const float* __restrict__ W_gnn,
                             bf16* __restrict__ Wcat) {
    int r = blockIdx.x;
    int e = threadIdx.x;
    float v = (r < 512) ? in_proj_w[r * E_ + e] : W_gnn[e * E_ + (r - 512)];
    Wcat[r * E_ + e] = (bf16)v;
}

// ---------------------------------------------------------------------------
// Kernel 2: projections (R2-proven config: grid (256,3)).
//   by==0 -> Qs[B,L,E]  (bias + QSCALE folded; col n = h*64+d)
//   by==1 -> Ks[B,L,E]  (bias folded)
//   by==2 -> XWT[B,E,L] = (x @ W_gnn + B_gnn)^T per batch, bf16
// ---------------------------------------------------------------------------
__global__ __launch_bounds__(256, 2) void proj_kernel(
    const float* __restrict__ x, const bf16* __restrict__ Wcat,
    const float* __restrict__ in_proj_b, const float* __restrict__ B_gnn,
    bf16* __restrict__ Qs, bf16* __restrict__ Ks, bf16* __restrict__ XWT) {
    int tid  = threadIdx.x;
    int lane = tid & 63, wave = tid >> 6;
    int l16  = lane & 15, quad = lane >> 4;
    int m0 = blockIdx.x * 64 + wave * 16;
    int by = blockIdx.y;
    int n0 = by * 256;

    f32x4 acc[16];
#pragma unroll
    for (int i = 0; i < 16; i++) acc[i] = (f32x4){0.f, 0.f, 0.f, 0.f};

    const float* xrow = x + (size_t)(m0 + l16) * E_;
    for (int ks = 0; ks < 8; ks++) {
        int koff = ks * 32 + quad * 8;
        f32x8 av = *(const f32x8*)&xrow[koff];
        bf16x8 af;
#pragma unroll
        for (int j = 0; j < 8; j++) af[j] = (bf16)av[j];
#pragma unroll
        for (int nt = 0; nt < 16; nt++) {
            bf16x8 bfv = *(const bf16x8*)&Wcat[(size_t)(n0 + nt * 16 + l16) * E_ + koff];
            acc[nt] = __builtin_amdgcn_mfma_f32_16x16x32_bf16(af, bfv, acc[nt], 0, 0, 0);
        }
    }

#pragma unroll
    for (int nt = 0; nt < 16; nt++) {
        int n = n0 + nt * 16 + l16;
        if (by == 0) {
            float bias = in_proj_b[n];
#pragma unroll
            for (int r = 0; r < 4; r++) {
                int m = m0 + quad * 4 + r;
                Qs[(size_t)m * E_ + n] = (bf16)((acc[nt][r] + bias) * QSCALE);
            }
        } else if (by == 1) {
            float bias = in_proj_b[n];
            int col = n - 256;
#pragma unroll
            for (int r = 0; r < 4; r++) {
                int m = m0 + quad * 4 + r;
                Ks[(size_t)m * E_ + col] = (bf16)(acc[nt][r] + bias);
            }
        } else {
            int nc = n - 512;
            float bias = B_gnn[nc];
            int m = m0 + quad * 4;
            int b = m >> 11, l = m & 2047;
            bf16x4 pk;
#pragma unroll
            for (int r = 0; r < 4; r++) pk[r] = (bf16)(acc[nt][r] + bias);
            *(bf16x4*)&XWT[((size_t)b * E_ + nc) * L_ + l] = pk;
        }
    }
}

// ---------------------------------------------------------------------------
// Kernel 3: softmax stats. o[b,h,q] = -log2(4 * sum_k exp2(Shat)).
// R2-proven config: grid (16,4,8)=512 blocks, 32q/wave.
// 32x32x16 C/D: col=lane&31, row=(reg&3)+8*(reg>>2)+4*(lane>>5).
// ---------------------------------------------------------------------------
__global__ __launch_bounds__(256, 4) void stats_kernel(
    const bf16* __restrict__ Qs, const bf16* __restrict__ Ks,
    float* __restrict__ o) {
    __shared__ bf16 ldsK[64 * 72];
    int tid  = threadIdx.x;
    int lane = tid & 63, wave = tid >> 6;
    int r32  = lane & 31, half = lane >> 5;
    int qt = blockIdx.x, h = blockIdx.y, b = blockIdx.z;
    int q0 = qt * 128 + wave * 32;

    bf16x8 qa[4];
    const bf16* qrow = Qs + ((size_t)b * L_ + q0 + r32) * E_ + h * D_;
#pragma unroll
    for (int c = 0; c < 4; c++) qa[c] = *(const bf16x8*)&qrow[c * 16 + half * 8];

    float lsum[16];
#pragma unroll
    for (int i = 0; i < 16; i++) lsum[i] = 0.f;

    const bf16* Kb = Ks + (size_t)b * L_ * E_ + h * D_;
    for (int kt = 0; kt < 32; kt++) {
        __syncthreads();
#pragma unroll
        for (int it = 0; it < 2; it++) {
            int idx = it * 256 + tid;
            int key = idx >> 3, dc = (idx & 7) * 8;
            *(bf16x8*)&ldsK[key * 72 + dc] =
                *(const bf16x8*)&Kb[(size_t)(kt * 64 + key) * E_ + dc];
        }
        __syncthreads();
#pragma unroll
        for (int nt = 0; nt < 2; nt++) {
            f32x16 S = {};
#pragma unroll
            for (int c = 0; c < 4; c++) {
                bf16x8 kb = *(const bf16x8*)&ldsK[(nt * 32 + r32) * 72 + c * 16 + half * 8];
                S = __builtin_amdgcn_mfma_f32_32x32x16_bf16(qa[c], kb, S, 0, 0, 0);
            }
#pragma unroll
            for (int i = 0; i < 16; i++) lsum[i] += fexp2(S[i]);
        }
    }
#pragma unroll
    for (int i = 0; i < 16; i++) {
        float v = lsum[i];
        v += __shfl_xor(v, 1); v += __shfl_xor(v, 2); v += __shfl_xor(v, 4);
        v += __shfl_xor(v, 8); v += __shfl_xor(v, 16);
        lsum[i] = v;
    }
    if (r32 == 0) {
        float* op = o + ((size_t)(b * H_ + h)) * L_ + q0;
#pragma unroll
        for (int i = 0; i < 16; i++) {
            int row = (i & 3) + 8 * (i >> 2) + 4 * half;
            op[row] = -(2.0f + flog2(lsum[i]));
        }
    }
}

// ---------------------------------------------------------------------------
// Kernel 4: pass 2 v7. 256-thr blocks, 4 waves x 32q (two 16q subtiles per
// wave share every B-frag read -> per-128q LDS ops ~halved vs R2), full
// n=256 per wave (no QK duplication -- R5's mistake). ksp=4 -> 512 blocks
// = 2 blocks/CU (cross-block barrier overlap, R2-proven). Register budget:
// acc 128 AGPR + ~110 VGPR (Q frags NOT resident: reloaded per head from
// the block-local 64 KB Q slice, L1/L2-hot, one-head prefetch). LDS exactly
// 80 KB (ldsP = 16-row per-wave regions, used in 2 rounds).
// ---------------------------------------------------------------------------
__global__ __launch_bounds__(256, 2) void pass2_kernel(
    const bf16* __restrict__ Qs, const bf16* __restrict__ Ks,
    const bf16* __restrict__ XWT, const float* __restrict__ o,
    bf16* __restrict__ Opart) {
    __shared__ bf16 ldsK[64 * 264];      // [64 keys][256 E + 8 pad]   33792 B
    __shared__ bf16 ldsXW[256 * 72];     // [256 n][64 k + 8 pad]      36864 B
    __shared__ bf16 ldsP[4][16 * 72];    // per-wave 16q region (2 rds) 9216 B
    __shared__ float ldsO[512];          //                             2048 B -> 81920 B

    int tid  = threadIdx.x;
    int lane = tid & 63, wave = tid >> 6;
    int l16  = lane & 15, quad = lane >> 4;
    int qt = blockIdx.x, ksp = blockIdx.y, b = blockIdx.z;
    int q0 = qt * 128 + wave * 32;

    // stage o table (512 f32)
#pragma unroll
    for (int j = tid; j < 512; j += 256)
        ldsO[j] = o[((size_t)(b * H_ + (j >> 7))) * L_ + qt * 128 + (j & 127)];

    const bf16* qp = Qs + ((size_t)b * L_ + q0 + l16) * E_;

    f32x4 acc[2][16];
#pragma unroll
    for (int s = 0; s < 2; s++)
#pragma unroll
        for (int i = 0; i < 16; i++) acc[s][i] = (f32x4){0.f, 0.f, 0.f, 0.f};

    const bf16* Kb = Ks + (size_t)b * L_ * E_;
    const bf16* Xb = XWT + (size_t)b * E_ * L_;
    int kbase = ksp * 512;

    for (int kt = 0; kt < 8; kt++) {
        int k0 = kbase + kt * 64;
        __syncthreads();
        // stage K tile: 64 keys x 256 E (serves all 4 heads)
#pragma unroll
        for (int it = 0; it < 8; it++) {
            int idx = it * 256 + tid;
            int key = idx >> 5, col = (idx & 31) * 8;
            *(bf16x8*)&ldsK[key * 264 + col] =
                *(const bf16x8*)&Kb[(size_t)(k0 + key) * E_ + col];
        }
        // stage XW tile: 256 n x 64 keys
#pragma unroll
        for (int it = 0; it < 8; it++) {
            int idx = it * 256 + tid;
            int n = idx >> 3, kc = (idx & 7) * 8;
            *(bf16x8*)&ldsXW[n * 72 + kc] =
                *(const bf16x8*)&Xb[(size_t)n * L_ + k0 + kc];
        }
        __syncthreads();

        // P = sum_h exp2(Shat_h + o_h); Q frags reloaded per head (hot),
        // prefetched one head ahead.
        f32x4 P[2][4];
#pragma unroll
        for (int s = 0; s < 2; s++)
#pragma unroll
            for (int nt = 0; nt < 4; nt++) P[s][nt] = (f32x4){0.f, 0.f, 0.f, 0.f};

        bf16x8 qn[2][2];
#pragma unroll
        for (int s = 0; s < 2; s++) {
            qn[s][0] = *(const bf16x8*)&qp[(size_t)s * 16 * E_ + quad * 8];
            qn[s][1] = *(const bf16x8*)&qp[(size_t)s * 16 * E_ + 32 + quad * 8];
        }
#pragma unroll
        for (int h = 0; h < H_; h++) {
            bf16x8 qc[2][2];
#pragma unroll
            for (int s = 0; s < 2; s++) { qc[s][0] = qn[s][0]; qc[s][1] = qn[s][1]; }
            if (h < 3) {
#pragma unroll
                for (int s = 0; s < 2; s++) {
                    qn[s][0] = *(const bf16x8*)&qp[(size_t)s * 16 * E_ + (h + 1) * 64 + quad * 8];
                    qn[s][1] = *(const bf16x8*)&qp[(size_t)s * 16 * E_ + (h + 1) * 64 + 32 + quad * 8];
                }
            }
            f32x4 S[2][4];
#pragma unroll
            for (int s = 0; s < 2; s++)
#pragma unroll
                for (int nt = 0; nt < 4; nt++) S[s][nt] = (f32x4){0.f, 0.f, 0.f, 0.f};
#pragma unroll
            for (int nt = 0; nt < 4; nt++) {
                bf16x8 k0f = *(const bf16x8*)&ldsK[(nt * 16 + l16) * 264 + h * 64 + quad * 8];
                bf16x8 k1f = *(const bf16x8*)&ldsK[(nt * 16 + l16) * 264 + h * 64 + 32 + quad * 8];
#pragma unroll
                for (int s = 0; s < 2; s++) {
                    S[s][nt] = __builtin_amdgcn_mfma_f32_16x16x32_bf16(qc[s][0], k0f, S[s][nt], 0, 0, 0);
                    S[s][nt] = __builtin_amdgcn_mfma_f32_16x16x32_bf16(qc[s][1], k1f, S[s][nt], 0, 0, 0);
                }
            }
#pragma unroll
            for (int s = 0; s < 2; s++)
#pragma unroll
                for (int r = 0; r < 4; r++) {
                    float off = ldsO[h * 128 + wave * 32 + s * 16 + quad * 4 + r];
#pragma unroll
                    for (int nt = 0; nt < 4; nt++)
                        P[s][nt][r] += fexp2(S[s][nt][r] + off);
                }
        }

        // P transpose (C->A/B layout) in 2 rounds through the 16-row
        // per-wave region (wave-private: no barrier; lgkmcnt orders it)
        bf16x8 pf[2][2];
#pragma unroll
        for (int s = 0; s < 2; s++) {
#pragma unroll
            for (int nt = 0; nt < 4; nt++)
#pragma unroll
                for (int r = 0; r < 4; r++)
                    ldsP[wave][(quad * 4 + r) * 72 + nt * 16 + l16] = (bf16)P[s][nt][r];
            pf[s][0] = *(const bf16x8*)&ldsP[wave][l16 * 72 + quad * 8];
            pf[s][1] = *(const bf16x8*)&ldsP[wave][l16 * 72 + 32 + quad * 8];
        }

        // PV (swapped): D[n][q] += XW[n][k] * P[q][k]; both subtiles share
        // each XW A-frag pair.
#pragma unroll
        for (int nt = 0; nt < 16; nt++) {
            bf16x8 a0 = *(const bf16x8*)&ldsXW[(nt * 16 + l16) * 72 + quad * 8];
            bf16x8 a1 = *(const bf16x8*)&ldsXW[(nt * 16 + l16) * 72 + 32 + quad * 8];
#pragma unroll
            for (int s = 0; s < 2; s++) {
                acc[s][nt] = __builtin_amdgcn_mfma_f32_16x16x32_bf16(a0, pf[s][0], acc[s][nt], 0, 0, 0);
                acc[s][nt] = __builtin_amdgcn_mfma_f32_16x16x32_bf16(a1, pf[s][1], acc[s][nt], 0, 0, 0);
            }
        }
    }

    // store: acc[s][nt] = D[n = nt*16+quad*4+r][q = q0+s*16+l16] -> b64 packs
    bf16* Ob = Opart + ((size_t)(ksp * B_ + b)) * L_ * E_;
#pragma unroll
    for (int s = 0; s < 2; s++) {
        size_t qrow = (size_t)(q0 + s * 16 + l16) * E_;
#pragma unroll
        for (int nt = 0; nt < 16; nt++) {
            bf16x4 pk;
#pragma unroll
            for (int r = 0; r < 4; r++) pk[r] = (bf16)acc[s][nt][r];
            *(bf16x4*)&Ob[qrow + nt * 16 + quad * 4] = pk;
        }
    }
}

// ---------------------------------------------------------------------------
// Kernel 5: sum the 4 k-split bf16 partials -> fp32 out[B,L,E]
// ---------------------------------------------------------------------------
__global__ void reduce_kernel(const bf16* __restrict__ Op, float* __restrict__ out) {
    size_t i = ((size_t)blockIdx.x * 256 + threadIdx.x) * 8;
    const size_t BLE = (size_t)B_ * L_ * E_;
    float s[8];
#pragma unroll
    for (int j = 0; j < 8; j++) s[j] = 0.f;
#pragma unroll
    for (int p = 0; p < 4; p++) {
        bf16x8 v = *(const bf16x8*)&Op[p * BLE + i];
#pragma unroll
        for (int j = 0; j < 8; j++) s[j] += (float)v[j];
    }
    f32x4 o0 = {s[0], s[1], s[2], s[3]}, o1 = {s[4], s[5], s[6], s[7]};
    *(f32x4*)&out[i] = o0;
    *(f32x4*)&out[i + 4] = o1;
}

// ---------------------------------------------------------------------------
extern "C" void kernel_launch(void* const* d_in, const int* in_sizes, int n_in,
                              void* d_out, int out_size, void* d_ws, size_t ws_size,
                              hipStream_t stream) {
    const float* x   = (const float*)d_in[0];
    const float* ipw = (const float*)d_in[1];
    const float* ipb = (const float*)d_in[2];
    const float* wg  = (const float*)d_in[3];
    const float* bg  = (const float*)d_in[4];

    char* ws = (char*)d_ws;
    // ws layout (bytes), total 58,982,400 (R2-proven size):
    //   Qs    [B,L,E]   bf16 @ 0          (8,388,608)
    //   Ks    [B,L,E]   bf16 @ 8388608    (8,388,608)
    //   XWT   [B,E,L]   bf16 @ 16777216   (8,388,608)
    //   o     [B,H,L]   f32  @ 25165824   (  262,144)
    //   Opart [4,B,L,E] bf16 @ 25427968   (33,554,432)
    //   Wcat  [768,256] bf16 @ 25427968   (overlaps Opart; dead before pass2)
    bf16*  Qs    = (bf16*)(ws);
    bf16*  Ks    = (bf16*)(ws + 8388608);
    bf16*  XWT   = (bf16*)(ws + 16777216);
    float* o     = (float*)(ws + 25165824);
    bf16*  Opart = (bf16*)(ws + 25427968);
    bf16*  Wcat  = (bf16*)(ws + 25427968);

    prep_weights<<<768, 256, 0, stream>>>(ipw, wg, Wcat);
    proj_kernel<<<dim3(256, 3), 256, 0, stream>>>(x, Wcat, ipb, bg, Qs, Ks, XWT);
    stats_kernel<<<dim3(16, 4, 8), 256, 0, stream>>>(Qs, Ks, o);
    pass2_kernel<<<dim3(16, 4, 8), 256, 0, stream>>>(Qs, Ks, XWT, o, Opart);
    reduce_kernel<<<2048, 256, 0, stream>>>(Opart, (float*)d_out);
}

// Round 7
// 241.936 us; speedup vs baseline: 1.2542x; 1.2542x over previous
//
#include <hip/hip_runtime.h>

#define B_ 8
#define L_ 2048
#define E_ 256
#define H_ 4
#define D_ 64

typedef __bf16 bf16;
typedef __bf16 bf16x8 __attribute__((ext_vector_type(8)));
typedef __bf16 bf16x4 __attribute__((ext_vector_type(4)));
typedef float  f32x4  __attribute__((ext_vector_type(4)));
typedef float  f32x8  __attribute__((ext_vector_type(8)));
typedef float  f32x16 __attribute__((ext_vector_type(16)));

// Shat = (q.k)/8 * log2(e); softmax entirely in exp2 domain.
#define QSCALE 0.1803368801111244f

__device__ __forceinline__ float fexp2(float x) { return __builtin_amdgcn_exp2f(x); }
__device__ __forceinline__ float flog2(float x) { return __builtin_amdgcn_logf(x); }

// ---------------------------------------------------------------------------
// Kernel 1: repack weights to bf16.
// ---------------------------------------------------------------------------
__global__ void prep_weights(const float* __restrict__ in_proj_w,
                             const float* __restrict__ W_gnn,
                             bf16* __restrict__ Wcat) {
    int r = blockIdx.x;
    int e = threadIdx.x;
    float v = (r < 512) ? in_proj_w[r * E_ + e] : W_gnn[e * E_ + (r - 512)];
    Wcat[r * E_ + e] = (bf16)v;
}

// ---------------------------------------------------------------------------
// Kernel 2: projections (R2-proven). by: 0->Qs[B,L,E], 1->Ks[B,L,E],
// 2->XWT[B,E,L] (bias folded everywhere; QSCALE folded into Q).
// ---------------------------------------------------------------------------
__global__ __launch_bounds__(256, 2) void proj_kernel(
    const float* __restrict__ x, const bf16* __restrict__ Wcat,
    const float* __restrict__ in_proj_b, const float* __restrict__ B_gnn,
    bf16* __restrict__ Qs, bf16* __restrict__ Ks, bf16* __restrict__ XWT) {
    int tid  = threadIdx.x;
    int lane = tid & 63, wave = tid >> 6;
    int l16  = lane & 15, quad = lane >> 4;
    int m0 = blockIdx.x * 64 + wave * 16;
    int by = blockIdx.y;
    int n0 = by * 256;

    f32x4 acc[16];
#pragma unroll
    for (int i = 0; i < 16; i++) acc[i] = (f32x4){0.f, 0.f, 0.f, 0.f};

    const float* xrow = x + (size_t)(m0 + l16) * E_;
    for (int ks = 0; ks < 8; ks++) {
        int koff = ks * 32 + quad * 8;
        f32x8 av = *(const f32x8*)&xrow[koff];
        bf16x8 af;
#pragma unroll
        for (int j = 0; j < 8; j++) af[j] = (bf16)av[j];
#pragma unroll
        for (int nt = 0; nt < 16; nt++) {
            bf16x8 bfv = *(const bf16x8*)&Wcat[(size_t)(n0 + nt * 16 + l16) * E_ + koff];
            acc[nt] = __builtin_amdgcn_mfma_f32_16x16x32_bf16(af, bfv, acc[nt], 0, 0, 0);
        }
    }

#pragma unroll
    for (int nt = 0; nt < 16; nt++) {
        int n = n0 + nt * 16 + l16;
        if (by == 0) {
            float bias = in_proj_b[n];
#pragma unroll
            for (int r = 0; r < 4; r++) {
                int m = m0 + quad * 4 + r;
                Qs[(size_t)m * E_ + n] = (bf16)((acc[nt][r] + bias) * QSCALE);
            }
        } else if (by == 1) {
            float bias = in_proj_b[n];
            int col = n - 256;
#pragma unroll
            for (int r = 0; r < 4; r++) {
                int m = m0 + quad * 4 + r;
                Ks[(size_t)m * E_ + col] = (bf16)(acc[nt][r] + bias);
            }
        } else {
            int nc = n - 512;
            float bias = B_gnn[nc];
            int m = m0 + quad * 4;
            int b = m >> 11, l = m & 2047;
            bf16x4 pk;
#pragma unroll
            for (int r = 0; r < 4; r++) pk[r] = (bf16)(acc[nt][r] + bias);
            *(bf16x4*)&XWT[((size_t)b * E_ + nc) * L_ + l] = pk;
        }
    }
}

// ---------------------------------------------------------------------------
// Kernel 3: softmax stats (R2-proven). o[b,h,q] = -log2(4*sum_k exp2(Shat)).
// ---------------------------------------------------------------------------
__global__ __launch_bounds__(256, 4) void stats_kernel(
    const bf16* __restrict__ Qs, const bf16* __restrict__ Ks,
    float* __restrict__ o) {
    __shared__ bf16 ldsK[64 * 72];
    int tid  = threadIdx.x;
    int lane = tid & 63, wave = tid >> 6;
    int r32  = lane & 31, half = lane >> 5;
    int qt = blockIdx.x, h = blockIdx.y, b = blockIdx.z;
    int q0 = qt * 128 + wave * 32;

    bf16x8 qa[4];
    const bf16* qrow = Qs + ((size_t)b * L_ + q0 + r32) * E_ + h * D_;
#pragma unroll
    for (int c = 0; c < 4; c++) qa[c] = *(const bf16x8*)&qrow[c * 16 + half * 8];

    float lsum[16];
#pragma unroll
    for (int i = 0; i < 16; i++) lsum[i] = 0.f;

    const bf16* Kb = Ks + (size_t)b * L_ * E_ + h * D_;
    for (int kt = 0; kt < 32; kt++) {
        __syncthreads();
#pragma unroll
        for (int it = 0; it < 2; it++) {
            int idx = it * 256 + tid;
            int key = idx >> 3, dc = (idx & 7) * 8;
            *(bf16x8*)&ldsK[key * 72 + dc] =
                *(const bf16x8*)&Kb[(size_t)(kt * 64 + key) * E_ + dc];
        }
        __syncthreads();
#pragma unroll
        for (int nt = 0; nt < 2; nt++) {
            f32x16 S = {};
#pragma unroll
            for (int c = 0; c < 4; c++) {
                bf16x8 kb = *(const bf16x8*)&ldsK[(nt * 32 + r32) * 72 + c * 16 + half * 8];
                S = __builtin_amdgcn_mfma_f32_32x32x16_bf16(qa[c], kb, S, 0, 0, 0);
            }
#pragma unroll
            for (int i = 0; i < 16; i++) lsum[i] += fexp2(S[i]);
        }
    }
#pragma unroll
    for (int i = 0; i < 16; i++) {
        float v = lsum[i];
        v += __shfl_xor(v, 1); v += __shfl_xor(v, 2); v += __shfl_xor(v, 4);
        v += __shfl_xor(v, 8); v += __shfl_xor(v, 16);
        lsum[i] = v;
    }
    if (r32 == 0) {
        float* op = o + ((size_t)(b * H_ + h)) * L_ + q0;
#pragma unroll
        for (int i = 0; i < 16; i++) {
            int row = (i & 3) + 8 * (i >> 2) + 4 * half;
            op[row] = -(2.0f + flog2(lsum[i]));
        }
    }
}

// ---------------------------------------------------------------------------
// Kernel 4 (big path): P-kernel. P[b,q,k] = sum_h exp2(Shat_h + o_h).
// QK only -> no accumulator -> 32q/wave WITH resident Q (no register wall).
// 32x32x16 MFMA operand-swapped (A=K, B=Q) so C cols = q = lane&31: the
// per-lane o offset is just 4 VGPRs. P written via wave-private LDS
// transpose -> coalesced b128 global stores. grid (16,4,8)=512, 2 blk/CU.
// ---------------------------------------------------------------------------
__global__ __launch_bounds__(256, 2) void pkernel(
    const bf16* __restrict__ Qs, const bf16* __restrict__ Ks,
    const float* __restrict__ o, bf16* __restrict__ P) {
    __shared__ bf16 ldsK[64 * 264];     // [64 keys][256 E + 8 pad] 33792 B
    __shared__ bf16 ldsT[4][32 * 72];   // per-wave [32 q][64 k+8]  18432 B

    int tid  = threadIdx.x;
    int lane = tid & 63, wave = tid >> 6;
    int r32  = lane & 31, half = lane >> 5;
    int qt = blockIdx.x, kc = blockIdx.y, b = blockIdx.z;
    int q = qt * 128 + wave * 32 + r32;        // this lane's q (col of C)

    // per-lane softmax offsets (4 VGPR)
    float oreg[4];
#pragma unroll
    for (int h = 0; h < H_; h++)
        oreg[h] = o[((size_t)(b * H_ + h)) * L_ + q];

    // resident Q B-frags: [head][kchunk], n=r32, k=c*16+half*8 (64 VGPR)
    bf16x8 qa[4][4];
    const bf16* qrow = Qs + ((size_t)b * L_ + q) * E_;
#pragma unroll
    for (int h = 0; h < H_; h++)
#pragma unroll
        for (int c = 0; c < 4; c++)
            qa[h][c] = *(const bf16x8*)&qrow[h * 64 + c * 16 + half * 8];

    const bf16* Kb = Ks + (size_t)b * L_ * E_;
    bf16* Pb = P + ((size_t)b * L_ + qt * 128 + wave * 32) * L_;

    for (int kt = 0; kt < 8; kt++) {
        int k0 = kc * 512 + kt * 64;
        __syncthreads();
#pragma unroll
        for (int it = 0; it < 8; it++) {
            int idx = it * 256 + tid;
            int key = idx >> 5, col = (idx & 31) * 8;
            *(bf16x8*)&ldsK[key * 264 + col] =
                *(const bf16x8*)&Kb[(size_t)(k0 + key) * E_ + col];
        }
        __syncthreads();

#pragma unroll
        for (int kg = 0; kg < 2; kg++) {
            f32x16 Pacc = {};
#pragma unroll
            for (int h = 0; h < H_; h++) {
                f32x16 S = {};
#pragma unroll
                for (int c = 0; c < 4; c++) {
                    bf16x8 kb = *(const bf16x8*)&ldsK[(kg * 32 + r32) * 264 + h * 64 + c * 16 + half * 8];
                    // A=K (m=key), B=Q (n=q): C[m=key][n=q], col=lane&31=q
                    S = __builtin_amdgcn_mfma_f32_32x32x16_bf16(kb, qa[h][c], S, 0, 0, 0);
                }
#pragma unroll
                for (int i = 0; i < 16; i++) Pacc[i] += fexp2(S[i] + oreg[h]);
            }
            // rows: key_local = (i&3) + 8*(i>>2) + 4*half + 32*kg
            // write transposed into wave-private LDS: [q=r32][key_local]
#pragma unroll
            for (int g2 = 0; g2 < 4; g2++) {
                bf16x4 pk;
#pragma unroll
                for (int r = 0; r < 4; r++) pk[r] = (bf16)Pacc[g2 * 4 + r];
                *(bf16x4*)&ldsT[wave][r32 * 72 + kg * 32 + g2 * 8 + half * 4] = pk;
            }
        }
        // readback rows along k -> coalesced global store of P[q][k0..k0+63]
#pragma unroll
        for (int it = 0; it < 4; it++) {
            int qrow_l = it * 8 + (lane >> 3);
            bf16x8 v = *(const bf16x8*)&ldsT[wave][qrow_l * 72 + (lane & 7) * 8];
            *(bf16x8*)&Pb[(size_t)qrow_l * L_ + k0 + (lane & 7) * 8] = v;
        }
    }
}

// ---------------------------------------------------------------------------
// Kernel 5 (big path): pure GEMM. Opart[kc] = P(kc-slice) @ XW.
// No Q, no exp2: acc 128 AGPR + ~60 VGPR -> 2 waves/SIMD. grid (16,4,8).
// D[m=c][n=q]: A=XWT[c][k], B=P[q][k].
// ---------------------------------------------------------------------------
__global__ __launch_bounds__(256, 2) void gemm_kernel(
    const bf16* __restrict__ P, const bf16* __restrict__ XWT,
    bf16* __restrict__ Opart) {
    __shared__ bf16 ldsXW[256 * 72];    // [256 c][64 k + 8 pad] 36864 B
    __shared__ bf16 ldsPt[128 * 72];    // [128 q][64 k + 8 pad] 18432 B

    int tid  = threadIdx.x;
    int lane = tid & 63, wave = tid >> 6;
    int l16  = lane & 15, quad = lane >> 4;
    int qt = blockIdx.x, kc = blockIdx.y, b = blockIdx.z;

    f32x4 acc[2][16];
#pragma unroll
    for (int s = 0; s < 2; s++)
#pragma unroll
        for (int i = 0; i < 16; i++) acc[s][i] = (f32x4){0.f, 0.f, 0.f, 0.f};

    const bf16* Xb = XWT + (size_t)b * E_ * L_;
    const bf16* Pb = P + ((size_t)b * L_ + qt * 128) * L_;

    for (int kt = 0; kt < 8; kt++) {
        int k0 = kc * 512 + kt * 64;
        __syncthreads();
#pragma unroll
        for (int it = 0; it < 8; it++) {
            int idx = it * 256 + tid;
            int n = idx >> 3, kc8 = (idx & 7) * 8;
            *(bf16x8*)&ldsXW[n * 72 + kc8] =
                *(const bf16x8*)&Xb[(size_t)n * L_ + k0 + kc8];
        }
#pragma unroll
        for (int it = 0; it < 4; it++) {
            int idx = it * 256 + tid;
            int qr = idx >> 3, kc8 = (idx & 7) * 8;
            *(bf16x8*)&ldsPt[qr * 72 + kc8] =
                *(const bf16x8*)&Pb[(size_t)qr * L_ + k0 + kc8];
        }
        __syncthreads();

        bf16x8 pf[2][2];
#pragma unroll
        for (int s = 0; s < 2; s++) {
            pf[s][0] = *(const bf16x8*)&ldsPt[(wave * 32 + s * 16 + l16) * 72 + quad * 8];
            pf[s][1] = *(const bf16x8*)&ldsPt[(wave * 32 + s * 16 + l16) * 72 + 32 + quad * 8];
        }
#pragma unroll
        for (int ct = 0; ct < 16; ct++) {
            bf16x8 a0 = *(const bf16x8*)&ldsXW[(ct * 16 + l16) * 72 + quad * 8];
            bf16x8 a1 = *(const bf16x8*)&ldsXW[(ct * 16 + l16) * 72 + 32 + quad * 8];
#pragma unroll
            for (int s = 0; s < 2; s++) {
                acc[s][ct] = __builtin_amdgcn_mfma_f32_16x16x32_bf16(a0, pf[s][0], acc[s][ct], 0, 0, 0);
                acc[s][ct] = __builtin_amdgcn_mfma_f32_16x16x32_bf16(a1, pf[s][1], acc[s][ct], 0, 0, 0);
            }
        }
    }

    // store: acc[s][ct] = D[c=ct*16+quad*4+r][q = qt*128+wave*32+s*16+l16]
    bf16* Ob = Opart + ((size_t)(kc * B_ + b)) * L_ * E_;
#pragma unroll
    for (int s = 0; s < 2; s++) {
        size_t qrow = (size_t)(qt * 128 + wave * 32 + s * 16 + l16) * E_;
#pragma unroll
        for (int ct = 0; ct < 16; ct++) {
            bf16x4 pk;
#pragma unroll
            for (int r = 0; r < 4; r++) pk[r] = (bf16)acc[s][ct][r];
            *(bf16x4*)&Ob[qrow + ct * 16 + quad * 4] = pk;
        }
    }
}

// ---------------------------------------------------------------------------
// Kernel 6 (big path): sum 4 bf16 partials -> fp32 out
// ---------------------------------------------------------------------------
__global__ void reduce4_kernel(const bf16* __restrict__ Op, float* __restrict__ out) {
    size_t i = ((size_t)blockIdx.x * 256 + threadIdx.x) * 8;
    const size_t BLE = (size_t)B_ * L_ * E_;
    float s[8];
#pragma unroll
    for (int j = 0; j < 8; j++) s[j] = 0.f;
#pragma unroll
    for (int p = 0; p < 4; p++) {
        bf16x8 v = *(const bf16x8*)&Op[p * BLE + i];
#pragma unroll
        for (int j = 0; j < 8; j++) s[j] += (float)v[j];
    }
    f32x4 o0 = {s[0], s[1], s[2], s[3]}, o1 = {s[4], s[5], s[6], s[7]};
    *(f32x4*)&out[i] = o0;
    *(f32x4*)&out[i + 4] = o1;
}

// ---------------------------------------------------------------------------
// Fallback (small ws): exact R2 fused pass2 (76.6 us proven) + f32 reduce2.
// ---------------------------------------------------------------------------
__global__ __launch_bounds__(256, 2) void pass2_fb(
    const bf16* __restrict__ Qs, const bf16* __restrict__ Ks,
    const bf16* __restrict__ XWT, const float* __restrict__ o,
    float* __restrict__ Opart) {
    __shared__ bf16 ldsK[64 * 264];
    __shared__ bf16 ldsXW[256 * 72];
    __shared__ bf16 ldsP[64 * 72];
    __shared__ float ldsO[4 * 128];

    int tid  = threadIdx.x;
    int lane = tid & 63, wave = tid >> 6;
    int l16  = lane & 15, quad = lane >> 4;
    int qt = blockIdx.x, ksp = blockIdx.y, b = blockIdx.z;
    int q0 = qt * 64 + wave * 16;

#pragma unroll
    for (int j = tid; j < 512; j += 256) {
        int h_ = j >> 7, i_ = j & 127;
        ldsO[j] = o[((size_t)(b * H_ + h_)) * L_ + qt * 64 + (i_ & 63) + (i_ >> 6) * 0];
    }
    // (o staged per 64-q block: only first 64 entries per head used)
    float orow[4][4];
#pragma unroll
    for (int h = 0; h < H_; h++)
#pragma unroll
        for (int r = 0; r < 4; r++)
            orow[h][r] = o[((size_t)(b * H_ + h)) * L_ + q0 + quad * 4 + r];

    bf16x8 qf[4][2];
    const bf16* qrow = Qs + ((size_t)b * L_ + q0 + l16) * E_;
#pragma unroll
    for (int h = 0; h < H_; h++) {
        qf[h][0] = *(const bf16x8*)&qrow[h * 64 + quad * 8];
        qf[h][1] = *(const bf16x8*)&qrow[h * 64 + 32 + quad * 8];
    }

    f32x4 acc[16];
#pragma unroll
    for (int i = 0; i < 16; i++) acc[i] = (f32x4){0.f, 0.f, 0.f, 0.f};

    const bf16* Kb = Ks + (size_t)b * L_ * E_;
    const bf16* Xb = XWT + (size_t)b * E_ * L_;

    for (int kt = 0; kt < 16; kt++) {
        int k0 = ksp * 1024 + kt * 64;
        __syncthreads();
#pragma unroll
        for (int it = 0; it < 8; it++) {
            int idx = it * 256 + tid;
            int key = idx >> 5, col = (idx & 31) * 8;
            *(bf16x8*)&ldsK[key * 264 + col] =
                *(const bf16x8*)&Kb[(size_t)(k0 + key) * E_ + col];
        }
#pragma unroll
        for (int it = 0; it < 8; it++) {
            int idx = it * 256 + tid;
            int n = idx >> 3, kc = (idx & 7) * 8;
            *(bf16x8*)&ldsXW[n * 72 + kc] =
                *(const bf16x8*)&Xb[(size_t)n * L_ + k0 + kc];
        }
        __syncthreads();

        f32x4 P[4];
#pragma unroll
        for (int nt = 0; nt < 4; nt++) P[nt] = (f32x4){0.f, 0.f, 0.f, 0.f};
#pragma unroll
        for (int h = 0; h < H_; h++) {
            f32x4 S[4];
#pragma unroll
            for (int nt = 0; nt < 4; nt++) S[nt] = (f32x4){0.f, 0.f, 0.f, 0.f};
#pragma unroll
            for (int nt = 0; nt < 4; nt++) {
                bf16x8 k0f = *(const bf16x8*)&ldsK[(nt * 16 + l16) * 264 + h * 64 + quad * 8];
                bf16x8 k1f = *(const bf16x8*)&ldsK[(nt * 16 + l16) * 264 + h * 64 + 32 + quad * 8];
                S[nt] = __builtin_amdgcn_mfma_f32_16x16x32_bf16(qf[h][0], k0f, S[nt], 0, 0, 0);
                S[nt] = __builtin_amdgcn_mfma_f32_16x16x32_bf16(qf[h][1], k1f, S[nt], 0, 0, 0);
            }
#pragma unroll
            for (int nt = 0; nt < 4; nt++)
#pragma unroll
                for (int r = 0; r < 4; r++)
                    P[nt][r] += fexp2(S[nt][r] + orow[h][r]);
        }

#pragma unroll
        for (int nt = 0; nt < 4; nt++)
#pragma unroll
            for (int r = 0; r < 4; r++)
                ldsP[(wave * 16 + quad * 4 + r) * 72 + nt * 16 + l16] = (bf16)P[nt][r];

        bf16x8 p0 = *(const bf16x8*)&ldsP[(wave * 16 + l16) * 72 + quad * 8];
        bf16x8 p1 = *(const bf16x8*)&ldsP[(wave * 16 + l16) * 72 + 32 + quad * 8];
#pragma unroll
        for (int nt = 0; nt < 16; nt++) {
            bf16x8 b0 = *(const bf16x8*)&ldsXW[(nt * 16 + l16) * 72 + quad * 8];
            bf16x8 b1 = *(const bf16x8*)&ldsXW[(nt * 16 + l16) * 72 + 32 + quad * 8];
            acc[nt] = __builtin_amdgcn_mfma_f32_16x16x32_bf16(p0, b0, acc[nt], 0, 0, 0);
            acc[nt] = __builtin_amdgcn_mfma_f32_16x16x32_bf16(p1, b1, acc[nt], 0, 0, 0);
        }
    }

    float* Ob = Opart + ((size_t)ksp * B_ + b) * L_ * E_ + (size_t)q0 * E_;
#pragma unroll
    for (int nt = 0; nt < 16; nt++)
#pragma unroll
        for (int r = 0; r < 4; r++)
            Ob[(size_t)(quad * 4 + r) * E_ + nt * 16 + l16] = acc[nt][r];
}

__global__ void reduce_fb(const float* __restrict__ Op, float* __restrict__ out) {
    size_t i = ((size_t)blockIdx.x * 256 + threadIdx.x) * 4;
    const size_t BLE = (size_t)B_ * L_ * E_;
    f32x4 a = *(const f32x4*)&Op[i];
    f32x4 c = *(const f32x4*)&Op[BLE + i];
#pragma unroll
    for (int j = 0; j < 4; j++) a[j] += c[j];
    *(f32x4*)&out[i] = a;
}

// ---------------------------------------------------------------------------
extern "C" void kernel_launch(void* const* d_in, const int* in_sizes, int n_in,
                              void* d_out, int out_size, void* d_ws, size_t ws_size,
                              hipStream_t stream) {
    const float* x   = (const float*)d_in[0];
    const float* ipw = (const float*)d_in[1];
    const float* ipb = (const float*)d_in[2];
    const float* wg  = (const float*)d_in[3];
    const float* bg  = (const float*)d_in[4];

    char* ws = (char*)d_ws;
    const size_t NEED_BIG = 126091264ULL;

    if (ws_size >= NEED_BIG) {
        // big layout:
        //   Qs    @ 0          (8,388,608)
        //   Ks    @ 8388608    (8,388,608)
        //   XWT   @ 16777216   (8,388,608)
        //   o     @ 25165824   (  262,144)
        //   P     @ 25427968   (67,108,864)  [B,L,L] bf16
        //   Opart @ 92536832   (33,554,432)  [4,B,L,E] bf16
        //   Wcat  @ 92536832   (overlaps Opart; dead before gemm)
        bf16*  Qs    = (bf16*)(ws);
        bf16*  Ks    = (bf16*)(ws + 8388608);
        bf16*  XWT   = (bf16*)(ws + 16777216);
        float* o     = (float*)(ws + 25165824);
        bf16*  P     = (bf16*)(ws + 25427968);
        bf16*  Opart = (bf16*)(ws + 92536832);
        bf16*  Wcat  = (bf16*)(ws + 92536832);

        prep_weights<<<768, 256, 0, stream>>>(ipw, wg, Wcat);
        proj_kernel<<<dim3(256, 3), 256, 0, stream>>>(x, Wcat, ipb, bg, Qs, Ks, XWT);
        stats_kernel<<<dim3(16, 4, 8), 256, 0, stream>>>(Qs, Ks, o);
        pkernel<<<dim3(16, 4, 8), 256, 0, stream>>>(Qs, Ks, o, P);
        gemm_kernel<<<dim3(16, 4, 8), 256, 0, stream>>>(P, XWT, Opart);
        reduce4_kernel<<<2048, 256, 0, stream>>>(Opart, (float*)d_out);
    } else {
        // fallback = exact R2 pipeline (proven 237 us), ws 58,982,400
        bf16*  Qs    = (bf16*)(ws);
        bf16*  Ks    = (bf16*)(ws + 8388608);
        bf16*  XWT   = (bf16*)(ws + 16777216);
        float* o     = (float*)(ws + 25165824);
        float* Opart = (float*)(ws + 25427968);
        bf16*  Wcat  = (bf16*)(ws + 33816576);

        prep_weights<<<768, 256, 0, stream>>>(ipw, wg, Wcat);
        proj_kernel<<<dim3(256, 3), 256, 0, stream>>>(x, Wcat, ipb, bg, Qs, Ks, XWT);
        stats_kernel<<<dim3(16, 4, 8), 256, 0, stream>>>(Qs, Ks, o);
        pass2_fb<<<dim3(32, 2, 8), 256, 0, stream>>>(Qs, Ks, XWT, o, Opart);
        reduce_fb<<<4096, 256, 0, stream>>>(Opart, (float*)d_out);
    }
}